// Round 4
// baseline (948.748 us; speedup 1.0000x reference)
//
#include <hip/hip_runtime.h>
#include <cstdint>
#include <cstddef>

// Causal self-attention. Inputs fp32 (R3-confirmed), output fp32 (R3 error
// signature). Compute: bf16 MFMA, fp32 accumulate.
// B=4 T=1024 C=2048 H=16 Dh=128.
//
// Pipeline (ws = flags + Q,K,VT,Y bf16 = ~67 MB):
//   1) qkv = x @ w_qkv  -> scatter Q[B,H,T,Dh], K[B,H,T,Dh], VT[B,H,Dh,T]
//   2) flash attention  -> Y[B,T,C] (bf16)
//   3) out = Y @ w_proj -> d_out (fp32)

typedef __attribute__((ext_vector_type(8))) __bf16 bf16x8;
typedef __attribute__((ext_vector_type(4))) float f32x4;
typedef unsigned short u16;

#define NEG_BIG (-1.0e30f)

__host__ __device__ __forceinline__ u16 f2bf(float f) {
    union { float f; uint32_t u; } v; v.f = f;
    uint32_t r = v.u + 0x7FFFu + ((v.u >> 16) & 1u);   // RNE
    return (u16)(r >> 16);
}

__device__ __forceinline__ uint32_t pack2(float a, float b) {
    return (uint32_t)f2bf(a) | ((uint32_t)f2bf(b) << 16);
}

__device__ __forceinline__ f32x4 mfma16(bf16x8 a, bf16x8 b, f32x4 c) {
    return __builtin_amdgcn_mfma_f32_16x16x32_bf16(a, b, c, 0, 0, 0);
}

// flag[0]: 1 if x is fp32, else 0. flag[1]: always 0 (bf16 marker for Y).
__global__ void detect_dtype(const uint32_t* __restrict__ x, int* __restrict__ flag) {
    __shared__ int cnt;
    if (threadIdx.x == 0) cnt = 0;
    __syncthreads();
    int local = 0;
    for (int i = threadIdx.x; i < 4096; i += 256) {
        uint32_t e = x[i] & 0x7F80u;
        if (e >= 0x3B80u && e <= 0x4100u) ++local;
    }
    atomicAdd(&cnt, local);
    __syncthreads();
    if (threadIdx.x == 0) { flag[0] = (cnt < 2048) ? 1 : 0; flag[1] = 0; }
}

// ---------------------------------------------------------------------------
// GEMM: C[M,N] = A[M,K] @ B[K,N], B native [K][N] (transposed into LDS).
// 128x128 tile, BK=32, 256 threads = 4 waves (64x64 each).
// aflag/bflag point at per-operand dtype ints (1 = fp32 data, 0 = bf16 u16).
// mode 0: fp32 store to outf[M,N]
// mode 1: bf16 scatter to Qo/Ko (B,H,T,Dh) and Vt (B,H,Dh,T)
// ---------------------------------------------------------------------------
__global__ __launch_bounds__(256) void gemm_bn(
    const void* __restrict__ Av, const void* __restrict__ Bv,
    int M, int N, int K, int mode,
    const int* __restrict__ aflag, const int* __restrict__ bflag,
    float* __restrict__ outf, u16* __restrict__ Qo, u16* __restrict__ Ko,
    u16* __restrict__ Vt) {
    __shared__ u16 As[128][32];
    __shared__ u16 Bs[128][32];   // Bs[n][k]

    const int af32 = aflag[0];
    const int bf32 = bflag[0];
    const u16*   A16 = (const u16*)Av;
    const float* A32 = (const float*)Av;
    const u16*   B16 = (const u16*)Bv;
    const float* B32 = (const float*)Bv;

    const int m0 = blockIdx.y * 128, n0 = blockIdx.x * 128;
    const int t = threadIdx.x;
    const int w = t >> 6, lane = t & 63;
    const int col = lane & 15, quad = lane >> 4;
    const int wrow = (w >> 1) * 64, wcol = (w & 1) * 64;

    f32x4 acc[4][4];
    #pragma unroll
    for (int i = 0; i < 4; ++i)
        #pragma unroll
        for (int j = 0; j < 4; ++j)
            acc[i][j] = (f32x4){0.f, 0.f, 0.f, 0.f};

    for (int k0 = 0; k0 < K; k0 += 32) {
        // A tile: 128 rows x 32 k
        #pragma unroll
        for (int c = t; c < 512; c += 256) {
            int r = c >> 2, cc = (c & 3) * 8;
            size_t off = (size_t)(m0 + r) * K + k0 + cc;
            if (!af32) {
                *(uint4*)&As[r][cc] = *(const uint4*)(A16 + off);
            } else {
                float4 u = *(const float4*)(A32 + off);
                float4 v = *(const float4*)(A32 + off + 4);
                uint4 p;
                p.x = pack2(u.x, u.y); p.y = pack2(u.z, u.w);
                p.z = pack2(v.x, v.y); p.w = pack2(v.z, v.w);
                *(uint4*)&As[r][cc] = p;
            }
        }
        // B tile: [32 k][128 n] native rows -> Bs[n][k]
        #pragma unroll
        for (int c = t; c < 512; c += 256) {
            int kk = c >> 4, nn = (c & 15) * 8;
            size_t off = (size_t)(k0 + kk) * N + n0 + nn;
            if (!bf32) {
                uint4 raw = *(const uint4*)(B16 + off);
                const u16* e = (const u16*)&raw;
                #pragma unroll
                for (int j = 0; j < 8; ++j) Bs[nn + j][kk] = e[j];
            } else {
                float4 u = *(const float4*)(B32 + off);
                float4 v = *(const float4*)(B32 + off + 4);
                Bs[nn + 0][kk] = f2bf(u.x); Bs[nn + 1][kk] = f2bf(u.y);
                Bs[nn + 2][kk] = f2bf(u.z); Bs[nn + 3][kk] = f2bf(u.w);
                Bs[nn + 4][kk] = f2bf(v.x); Bs[nn + 5][kk] = f2bf(v.y);
                Bs[nn + 6][kk] = f2bf(v.z); Bs[nn + 7][kk] = f2bf(v.w);
            }
        }
        __syncthreads();

        bf16x8 afr[4], bfr[4];
        #pragma unroll
        for (int i = 0; i < 4; ++i)
            afr[i] = *(const bf16x8*)&As[wrow + i * 16 + col][quad * 8];
        #pragma unroll
        for (int i = 0; i < 4; ++i)
            bfr[i] = *(const bf16x8*)&Bs[wcol + i * 16 + col][quad * 8];

        #pragma unroll
        for (int mt = 0; mt < 4; ++mt)
            #pragma unroll
            for (int nt = 0; nt < 4; ++nt)
                acc[mt][nt] = mfma16(afr[mt], bfr[nt], acc[mt][nt]);
        __syncthreads();
    }

    // epilogue: C/D layout col = lane&15, row = quad*4 + r  (m89-verified)
    #pragma unroll
    for (int mt = 0; mt < 4; ++mt) {
        #pragma unroll
        for (int nt = 0; nt < 4; ++nt) {
            #pragma unroll
            for (int r = 0; r < 4; ++r) {
                int gm = m0 + wrow + mt * 16 + quad * 4 + r;
                int gn = n0 + wcol + nt * 16 + col;
                if (mode == 0) {
                    outf[(size_t)gm * N + gn] = acc[mt][nt][r];
                } else {
                    u16 bv = f2bf(acc[mt][nt][r]);
                    int b = gm >> 10, tq = gm & 1023;
                    int which = gn >> 11, rem = gn & 2047;
                    int h = rem >> 7, d = rem & 127;
                    size_t bh = (size_t)b * 16 + h;
                    if (which == 0)      Qo[(bh * 1024 + tq) * 128 + d] = bv;
                    else if (which == 1) Ko[(bh * 1024 + tq) * 128 + d] = bv;
                    else                 Vt[(bh * 128 + d) * 1024 + tq] = bv;
                }
            }
        }
    }
}

// ---------------------------------------------------------------------------
// Flash attention. Grid (T/64, H, B), 256 threads = 4 waves.
// ---------------------------------------------------------------------------
__global__ __launch_bounds__(256) void attn_kernel(
    const u16* __restrict__ Q, const u16* __restrict__ K,
    const u16* __restrict__ VT, u16* __restrict__ Y) {
    __shared__ u16 Ks[64][128];
    __shared__ u16 Vs[128][64];
    __shared__ u16 Ps[4][16][64];

    const int qb = blockIdx.x, h = blockIdx.y, b = blockIdx.z;
    const int t = threadIdx.x;
    const int w = t >> 6, lane = t & 63;
    const int col = lane & 15, quad = lane >> 4;
    const size_t bh = (size_t)b * 16 + h;
    const u16* Qb = Q + bh * 1024 * 128;
    const u16* Kb = K + bh * 1024 * 128;
    const u16* Vb = VT + bh * 128 * 1024;
    const int qrow_w = qb * 64 + w * 16;

    bf16x8 qf[4];
    {
        const u16* qp = Qb + (size_t)(qrow_w + col) * 128 + quad * 8;
        #pragma unroll
        for (int kq = 0; kq < 4; ++kq)
            qf[kq] = *(const bf16x8*)(qp + kq * 32);
    }

    f32x4 o[8];
    #pragma unroll
    for (int i = 0; i < 8; ++i) o[i] = (f32x4){0.f, 0.f, 0.f, 0.f};
    float mrow[4], lrow[4];
    #pragma unroll
    for (int r = 0; r < 4; ++r) { mrow[r] = NEG_BIG; lrow[r] = 0.f; }

    const float scale = 0.08838834764831845f;  // 1/sqrt(128)
    const int nkt = qb + 1;

    for (int kt = 0; kt < nkt; ++kt) {
        #pragma unroll
        for (int c = t; c < 1024; c += 256) {
            int row = c >> 4, cc = (c & 15) * 8;
            *(uint4*)&Ks[row][cc] =
                *(const uint4*)(Kb + (size_t)(kt * 64 + row) * 128 + cc);
        }
        #pragma unroll
        for (int c = t; c < 1024; c += 256) {
            int d = c >> 3, cc = (c & 7) * 8;
            *(uint4*)&Vs[d][cc] =
                *(const uint4*)(Vb + (size_t)d * 1024 + kt * 64 + cc);
        }
        __syncthreads();

        f32x4 s[4];
        #pragma unroll
        for (int nt = 0; nt < 4; ++nt) {
            f32x4 a = (f32x4){0.f, 0.f, 0.f, 0.f};
            #pragma unroll
            for (int kq = 0; kq < 4; ++kq) {
                bf16x8 kf = *(const bf16x8*)&Ks[nt * 16 + col][kq * 32 + quad * 8];
                a = mfma16(qf[kq], kf, a);
            }
            s[nt] = a;
        }

        const bool need_mask = (kt == qb);
        float rmax[4];
        #pragma unroll
        for (int r = 0; r < 4; ++r) rmax[r] = NEG_BIG;
        #pragma unroll
        for (int nt = 0; nt < 4; ++nt) {
            int kcol = kt * 64 + nt * 16 + col;
            #pragma unroll
            for (int r = 0; r < 4; ++r) {
                float v = s[nt][r] * scale;
                int qr = qrow_w + quad * 4 + r;
                if (need_mask && kcol > qr) v = NEG_BIG;
                s[nt][r] = v;
                rmax[r] = fmaxf(rmax[r], v);
            }
        }
        #pragma unroll
        for (int msk = 1; msk < 16; msk <<= 1)
            #pragma unroll
            for (int r = 0; r < 4; ++r)
                rmax[r] = fmaxf(rmax[r], __shfl_xor(rmax[r], msk, 64));

        float alpha[4], rsum[4];
        #pragma unroll
        for (int r = 0; r < 4; ++r) {
            float mnew = fmaxf(mrow[r], rmax[r]);
            alpha[r] = __expf(mrow[r] - mnew);
            mrow[r] = mnew;
            rsum[r] = 0.f;
        }
        #pragma unroll
        for (int nt = 0; nt < 4; ++nt) {
            #pragma unroll
            for (int r = 0; r < 4; ++r) {
                float p = __expf(s[nt][r] - mrow[r]);
                rsum[r] += p;
                Ps[w][quad * 4 + r][nt * 16 + col] = f2bf(p);
            }
        }
        #pragma unroll
        for (int msk = 1; msk < 16; msk <<= 1)
            #pragma unroll
            for (int r = 0; r < 4; ++r)
                rsum[r] += __shfl_xor(rsum[r], msk, 64);
        #pragma unroll
        for (int r = 0; r < 4; ++r) lrow[r] = lrow[r] * alpha[r] + rsum[r];
        #pragma unroll
        for (int dt = 0; dt < 8; ++dt)
            #pragma unroll
            for (int r = 0; r < 4; ++r) o[dt][r] *= alpha[r];

        #pragma unroll
        for (int ks = 0; ks < 2; ++ks) {
            bf16x8 pf = *(const bf16x8*)&Ps[w][col][ks * 32 + quad * 8];
            #pragma unroll
            for (int dt = 0; dt < 8; ++dt) {
                bf16x8 vf = *(const bf16x8*)&Vs[dt * 16 + col][ks * 32 + quad * 8];
                o[dt] = mfma16(pf, vf, o[dt]);
            }
        }
        __syncthreads();
    }

    #pragma unroll
    for (int dt = 0; dt < 8; ++dt) {
        #pragma unroll
        for (int r = 0; r < 4; ++r) {
            int tq = qrow_w + quad * 4 + r;
            float v = o[dt][r] / lrow[r];
            Y[((size_t)b * 1024 + tq) * 2048 + h * 128 + dt * 16 + col] = f2bf(v);
        }
    }
}

// ---------------------------------------------------------------------------
extern "C" void kernel_launch(void* const* d_in, const int* in_sizes, int n_in,
                              void* d_out, int out_size, void* d_ws, size_t ws_size,
                              hipStream_t stream) {
    const void* x      = d_in[0];   // [4096, 2048] fp32
    const void* w_qkv  = d_in[1];   // [2048, 6144] fp32
    const void* w_proj = d_in[2];   // [2048, 2048] fp32
    float* out = (float*)d_out;     // [4096, 2048] fp32

    const size_t SEG = (size_t)4 * 16 * 1024 * 128;   // 8,388,608 elements

    int* flag = (int*)d_ws;          // flag[0]=input dtype, flag[1]=0 (bf16)
    u16* Qo = (u16*)((char*)d_ws + 256);
    u16* Ko = Qo + SEG;
    u16* Vt = Ko + SEG;
    u16* Y  = Vt + SEG;

    detect_dtype<<<1, 256, 0, stream>>>((const uint32_t*)x, flag);

    gemm_bn<<<dim3(48, 32), 256, 0, stream>>>(x, w_qkv, 4096, 6144, 2048, 1,
                                              flag, flag, nullptr, Qo, Ko, Vt);

    attn_kernel<<<dim3(16, 16, 4), 256, 0, stream>>>(Qo, Ko, Vt, Y);

    // A = Y (bf16 -> flag+1 which is 0), B = w_proj (input dtype -> flag)
    gemm_bn<<<dim3(16, 32), 256, 0, stream>>>(Y, w_proj, 4096, 2048, 2048, 0,
                                              flag + 1, flag, out, nullptr, nullptr, nullptr);
}

// Round 5
// 625.014 us; speedup vs baseline: 1.5180x; 1.5180x over previous
//
#include <hip/hip_runtime.h>
#include <cstdint>
#include <cstddef>

// Causal self-attention. fp32 in / fp32 out (R4-verified). bf16 MFMA compute.
// B=4 T=1024 C=2048 H=16 Dh=128.
//
// R5: (1) weights pre-transposed per-slice to bf16 [N][K] (kills the 16-way
// bank-conflict in-LDS transpose that made R4's GEMM 8% MfmaUtil);
// (2) B-tile staged via global_load_lds width=16 (m97 ladder step);
// (3) attention LDS padded (stride = 4 mod 32 banks), O written in-place
// into Q so proj GEMM reads BHTD layout; ws = 8.4 + 3*16.8 = 58.7 MB.

typedef __attribute__((ext_vector_type(8))) __bf16 bf16x8;
typedef __attribute__((ext_vector_type(4))) float f32x4;
typedef unsigned short u16;

#define NEG_BIG (-1.0e30f)

__device__ __forceinline__ u16 f2bf(float f) {
    union { float f; uint32_t u; } v; v.f = f;
    uint32_t r = v.u + 0x7FFFu + ((v.u >> 16) & 1u);   // RNE
    return (u16)(r >> 16);
}

__device__ __forceinline__ uint32_t pack2(float a, float b) {
    return (uint32_t)f2bf(a) | ((uint32_t)f2bf(b) << 16);
}

__device__ __forceinline__ f32x4 mfma16(bf16x8 a, bf16x8 b, f32x4 c) {
    return __builtin_amdgcn_mfma_f32_16x16x32_bf16(a, b, c, 0, 0, 0);
}

// async global->LDS, 16B per lane; lds dst must be wave-uniform base (+lane*16)
__device__ __forceinline__ void async16(const u16* g, u16* l) {
    __builtin_amdgcn_global_load_lds(
        (const __attribute__((address_space(1))) void*)g,
        (__attribute__((address_space(3))) void*)l, 16, 0, 0);
}

// ---------------------------------------------------------------------------
// Transpose+convert: W fp32 [2048 x ldW] slice (2048 cols) -> WT bf16 [2048][2048]
// 64x64 tiles, padded LDS. Grid (32, 32).
// ---------------------------------------------------------------------------
__global__ __launch_bounds__(256) void transpose_w(
    const float* __restrict__ W, int ldW, u16* __restrict__ WT) {
    __shared__ u16 tile[64][68];
    const int n0 = blockIdx.x * 64, k0 = blockIdx.y * 64;
    const int t = threadIdx.x;
    for (int i = t; i < 4096; i += 256) {
        int r = i >> 6, c = i & 63;
        tile[r][c] = f2bf(W[(size_t)(k0 + r) * ldW + n0 + c]);
    }
    __syncthreads();
    for (int i = t; i < 4096; i += 256) {
        int r = i >> 6, c = i & 63;          // r: n, c: k
        WT[(size_t)(n0 + r) * 2048 + k0 + c] = tile[c][r];
    }
}

// ---------------------------------------------------------------------------
// GEMM: C[M,N] = A[M,K] @ Bt[N,K], K=N=2048, M=4096. 128x128 tile, BK=32.
// 256 threads = 4 waves, each 64x64 (4x4 MFMA of 16x16x32).
// amode 0: A fp32 flat [M][K] (converted in staging)
// amode 1: A bf16 in [B,H,T,Dh] layout (m=b*1024+t, k=h*128+d)
// omode 0: fp32 store outf[M][N]
// omode 1: bf16 scatter outb[((b*16+h)*1024+t)*128+d]   (Q/K)
// omode 2: bf16 scatter outb[((b*16+h)*128+d)*1024+t]   (V^T)
// ---------------------------------------------------------------------------
__global__ __launch_bounds__(256) void gemm_k(
    const void* __restrict__ Av, const u16* __restrict__ Bt,
    int amode, int omode,
    float* __restrict__ outf, u16* __restrict__ outb) {
    const int M = 4096, N = 2048, K = 2048;
    __shared__ u16 As[128][32];
    __shared__ u16 Bs[128][32];   // Bs[n][k], contiguous for global_load_lds

    const float* A32 = (const float*)Av;
    const u16*   A16 = (const u16*)Av;

    const int m0 = blockIdx.y * 128, n0 = blockIdx.x * 128;
    const int t = threadIdx.x;
    const int w = t >> 6, lane = t & 63;
    const int col = lane & 15, quad = lane >> 4;
    const int wrow = (w >> 1) * 64, wcol = (w & 1) * 64;

    f32x4 acc[4][4];
    #pragma unroll
    for (int i = 0; i < 4; ++i)
        #pragma unroll
        for (int j = 0; j < 4; ++j)
            acc[i][j] = (f32x4){0.f, 0.f, 0.f, 0.f};

    u16* bs_flat = &Bs[0][0];

    for (int k0 = 0; k0 < K; k0 += 32) {
        // ---- B tile: 128x32 bf16 via async direct-to-LDS (2 chunks/lane) ----
        {
            int c1 = (w << 6) | lane;                       // 0..255
            const u16* g1 = Bt + (size_t)(n0 + (c1 >> 2)) * K + k0 + ((c1 & 3) << 3);
            async16(g1, bs_flat + (size_t)w * 512);
            int c2 = c1 + 256;                              // 256..511
            const u16* g2 = Bt + (size_t)(n0 + (c2 >> 2)) * K + k0 + ((c2 & 3) << 3);
            async16(g2, bs_flat + 2048 + (size_t)w * 512);
        }
        // ---- A tile: 128x32, VGPR staging ----
        #pragma unroll
        for (int c = t; c < 512; c += 256) {
            int r = c >> 2, ko = (c & 3) * 8;
            if (amode == 0) {
                size_t off = (size_t)(m0 + r) * K + k0 + ko;
                float4 u = *(const float4*)(A32 + off);
                float4 v = *(const float4*)(A32 + off + 4);
                uint4 p;
                p.x = pack2(u.x, u.y); p.y = pack2(u.z, u.w);
                p.z = pack2(v.x, v.y); p.w = pack2(v.z, v.w);
                *(uint4*)&As[r][ko] = p;
            } else {
                int kg = k0 + ko;
                int h = kg >> 7, d = kg & 127;
                int m = m0 + r;
                int b = m >> 10, tt = m & 1023;
                *(uint4*)&As[r][ko] =
                    *(const uint4*)(A16 + (((size_t)(b * 16 + h)) * 1024 + tt) * 128 + d);
            }
        }
        __syncthreads();   // drains vmcnt (async B) + lgkmcnt (A ds_writes)

        bf16x8 afr[4], bfr[4];
        #pragma unroll
        for (int i = 0; i < 4; ++i)
            afr[i] = *(const bf16x8*)&As[wrow + i * 16 + col][quad * 8];
        #pragma unroll
        for (int i = 0; i < 4; ++i)
            bfr[i] = *(const bf16x8*)&Bs[wcol + i * 16 + col][quad * 8];

        #pragma unroll
        for (int mt = 0; mt < 4; ++mt)
            #pragma unroll
            for (int nt = 0; nt < 4; ++nt)
                acc[mt][nt] = mfma16(afr[mt], bfr[nt], acc[mt][nt]);
        __syncthreads();
    }

    // epilogue: C/D layout col = lane&15, row = quad*4 + r  (m89-verified)
    #pragma unroll
    for (int mt = 0; mt < 4; ++mt) {
        #pragma unroll
        for (int nt = 0; nt < 4; ++nt) {
            #pragma unroll
            for (int r = 0; r < 4; ++r) {
                int gm = m0 + wrow + mt * 16 + quad * 4 + r;
                int gn = n0 + wcol + nt * 16 + col;
                if (omode == 0) {
                    outf[(size_t)gm * N + gn] = acc[mt][nt][r];
                } else {
                    u16 bv = f2bf(acc[mt][nt][r]);
                    int b = gm >> 10, tq = gm & 1023;
                    int h = gn >> 7, d = gn & 127;
                    size_t bh = (size_t)b * 16 + h;
                    if (omode == 1) outb[(bh * 1024 + tq) * 128 + d] = bv;
                    else            outb[(bh * 128 + d) * 1024 + tq] = bv;
                }
            }
        }
    }
}

// ---------------------------------------------------------------------------
// Flash attention. Grid (T/64, H, B), 256 threads = 4 waves; wave = 16 q-rows.
// LDS padded so frag-read bank stride = 4 mod 32 (2-way = free, m136).
// O overwrites Q in place (q-rows are block-private).
// ---------------------------------------------------------------------------
__global__ __launch_bounds__(256) void attn_kernel(
    u16* __restrict__ Q, const u16* __restrict__ K,
    const u16* __restrict__ VT) {
    __shared__ u16 Ks[64][136];
    __shared__ u16 Vs[128][72];
    __shared__ u16 Ps[4][16][72];

    const int qb = blockIdx.x, h = blockIdx.y, b = blockIdx.z;
    const int t = threadIdx.x;
    const int w = t >> 6, lane = t & 63;
    const int col = lane & 15, quad = lane >> 4;
    const size_t bh = (size_t)b * 16 + h;
    u16* Qb = Q + bh * 1024 * 128;
    const u16* Kb = K + bh * 1024 * 128;
    const u16* Vb = VT + bh * 128 * 1024;
    const int qrow_w = qb * 64 + w * 16;

    bf16x8 qf[4];
    {
        const u16* qp = Qb + (size_t)(qrow_w + col) * 128 + quad * 8;
        #pragma unroll
        for (int kq = 0; kq < 4; ++kq)
            qf[kq] = *(const bf16x8*)(qp + kq * 32);
    }

    f32x4 o[8];
    #pragma unroll
    for (int i = 0; i < 8; ++i) o[i] = (f32x4){0.f, 0.f, 0.f, 0.f};
    float mrow[4], lrow[4];
    #pragma unroll
    for (int r = 0; r < 4; ++r) { mrow[r] = NEG_BIG; lrow[r] = 0.f; }

    const float scale = 0.08838834764831845f;  // 1/sqrt(128)
    const int nkt = qb + 1;

    for (int kt = 0; kt < nkt; ++kt) {
        #pragma unroll
        for (int c = t; c < 1024; c += 256) {
            int row = c >> 4, cc = (c & 15) * 8;
            *(uint4*)&Ks[row][cc] =
                *(const uint4*)(Kb + (size_t)(kt * 64 + row) * 128 + cc);
        }
        #pragma unroll
        for (int c = t; c < 1024; c += 256) {
            int d = c >> 3, cc = (c & 7) * 8;
            *(uint4*)&Vs[d][cc] =
                *(const uint4*)(Vb + (size_t)d * 1024 + kt * 64 + cc);
        }
        __syncthreads();

        f32x4 s[4];
        #pragma unroll
        for (int nt = 0; nt < 4; ++nt) {
            f32x4 a = (f32x4){0.f, 0.f, 0.f, 0.f};
            #pragma unroll
            for (int kq = 0; kq < 4; ++kq) {
                bf16x8 kf = *(const bf16x8*)&Ks[nt * 16 + col][kq * 32 + quad * 8];
                a = mfma16(qf[kq], kf, a);
            }
            s[nt] = a;
        }

        const bool need_mask = (kt == qb);
        float rmax[4];
        #pragma unroll
        for (int r = 0; r < 4; ++r) rmax[r] = NEG_BIG;
        #pragma unroll
        for (int nt = 0; nt < 4; ++nt) {
            int kcol = kt * 64 + nt * 16 + col;
            #pragma unroll
            for (int r = 0; r < 4; ++r) {
                float v = s[nt][r] * scale;
                int qr = qrow_w + quad * 4 + r;
                if (need_mask && kcol > qr) v = NEG_BIG;
                s[nt][r] = v;
                rmax[r] = fmaxf(rmax[r], v);
            }
        }
        #pragma unroll
        for (int msk = 1; msk < 16; msk <<= 1)
            #pragma unroll
            for (int r = 0; r < 4; ++r)
                rmax[r] = fmaxf(rmax[r], __shfl_xor(rmax[r], msk, 64));

        float alpha[4], rsum[4];
        #pragma unroll
        for (int r = 0; r < 4; ++r) {
            float mnew = fmaxf(mrow[r], rmax[r]);
            alpha[r] = __expf(mrow[r] - mnew);
            mrow[r] = mnew;
            rsum[r] = 0.f;
        }
        #pragma unroll
        for (int nt = 0; nt < 4; ++nt) {
            #pragma unroll
            for (int r = 0; r < 4; ++r) {
                float p = __expf(s[nt][r] - mrow[r]);
                rsum[r] += p;
                Ps[w][quad * 4 + r][nt * 16 + col] = f2bf(p);
            }
        }
        #pragma unroll
        for (int msk = 1; msk < 16; msk <<= 1)
            #pragma unroll
            for (int r = 0; r < 4; ++r)
                rsum[r] += __shfl_xor(rsum[r], msk, 64);
        #pragma unroll
        for (int r = 0; r < 4; ++r) lrow[r] = lrow[r] * alpha[r] + rsum[r];
        #pragma unroll
        for (int dt = 0; dt < 8; ++dt)
            #pragma unroll
            for (int r = 0; r < 4; ++r) o[dt][r] *= alpha[r];

        #pragma unroll
        for (int ks = 0; ks < 2; ++ks) {
            bf16x8 pf = *(const bf16x8*)&Ps[w][col][ks * 32 + quad * 8];
            #pragma unroll
            for (int dt = 0; dt < 8; ++dt) {
                bf16x8 vf = *(const bf16x8*)&Vs[dt * 16 + col][ks * 32 + quad * 8];
                o[dt] = mfma16(pf, vf, o[dt]);
            }
        }
        __syncthreads();
    }

    // epilogue: O -> Q buffer in place (same [B,H,T,Dh] layout)
    #pragma unroll
    for (int dt = 0; dt < 8; ++dt) {
        #pragma unroll
        for (int r = 0; r < 4; ++r) {
            int tq = qrow_w + quad * 4 + r;
            Qb[((size_t)tq) * 128 + dt * 16 + col] = f2bf(o[dt][r] / lrow[r]);
        }
    }
}

// ---------------------------------------------------------------------------
extern "C" void kernel_launch(void* const* d_in, const int* in_sizes, int n_in,
                              void* d_out, int out_size, void* d_ws, size_t ws_size,
                              hipStream_t stream) {
    const float* x      = (const float*)d_in[0];   // [4096, 2048]
    const float* w_qkv  = (const float*)d_in[1];   // [2048, 6144]
    const float* w_proj = (const float*)d_in[2];   // [2048, 2048]
    float* out = (float*)d_out;                    // [4096, 2048]

    const size_t SEG = (size_t)4 * 16 * 1024 * 128;   // 8,388,608 elements
    u16* wT = (u16*)d_ws;                 // 2048*2048 bf16, reused 4x
    u16* Qb = wT + (size_t)2048 * 2048;
    u16* Kb = Qb + SEG;
    u16* Vb = Kb + SEG;                   // total 58.7 MB

    const dim3 gT(32, 32), gG(16, 32);

    // Q = x @ Wq
    transpose_w<<<gT, 256, 0, stream>>>(w_qkv + 0, 6144, wT);
    gemm_k<<<gG, 256, 0, stream>>>(x, wT, 0, 1, nullptr, Qb);
    // K = x @ Wk
    transpose_w<<<gT, 256, 0, stream>>>(w_qkv + 2048, 6144, wT);
    gemm_k<<<gG, 256, 0, stream>>>(x, wT, 0, 1, nullptr, Kb);
    // V^T = (x @ Wv)^T
    transpose_w<<<gT, 256, 0, stream>>>(w_qkv + 4096, 6144, wT);
    gemm_k<<<gG, 256, 0, stream>>>(x, wT, 0, 2, nullptr, Vb);

    // attention, O overwrites Q
    attn_kernel<<<dim3(16, 16, 4), 256, 0, stream>>>(Qb, Kb, Vb);

    // out = O @ w_proj   (A in BHTD layout)
    transpose_w<<<gT, 256, 0, stream>>>(w_proj, 2048, wT);
    gemm_k<<<gG, 256, 0, stream>>>(Qb, wT, 1, 0, out, nullptr);
}

// Round 6
// 487.854 us; speedup vs baseline: 1.9447x; 1.2811x over previous
//
#include <hip/hip_runtime.h>
#include <cstdint>
#include <cstddef>

// Causal self-attention. fp32 in / fp32 out. bf16 MFMA compute, fp32 accum.
// B=4 T=1024 C=2048 H=16 Dh=128.
//
// R6 fast path (ws >= 93 MB):
//   wqkvT = transpose(w_qkv) bf16 [6144][2048];  xb = bf16(x) [4096][2048]
//   QKV = xb @ wqkvT   -- ONE gemm, 48x32=1536 blocks, BOTH operands staged
//                         via global_load_lds width=16 (m97 structure)
//   flash attention (O overwrites Q), qb launch order reversed (heavy first)
//   out = O @ wprojT   -- A gathered from BHTD via per-lane async16
// Fallback (67 <= ws < 93 MB): R5-proven sequence (fp32 VGPR A-staging).

typedef __attribute__((ext_vector_type(8))) __bf16 bf16x8;
typedef __attribute__((ext_vector_type(4))) float f32x4;
typedef unsigned short u16;

#define NEG_BIG (-1.0e30f)

__device__ __forceinline__ u16 f2bf(float f) {
    union { float f; uint32_t u; } v; v.f = f;
    uint32_t r = v.u + 0x7FFFu + ((v.u >> 16) & 1u);   // RNE
    return (u16)(r >> 16);
}

__device__ __forceinline__ uint32_t pack2(float a, float b) {
    return (uint32_t)f2bf(a) | ((uint32_t)f2bf(b) << 16);
}

__device__ __forceinline__ f32x4 mfma16(bf16x8 a, bf16x8 b, f32x4 c) {
    return __builtin_amdgcn_mfma_f32_16x16x32_bf16(a, b, c, 0, 0, 0);
}

// async global->LDS, 16B/lane; LDS dst = wave-uniform base + lane*16
__device__ __forceinline__ void async16(const u16* g, u16* l) {
    __builtin_amdgcn_global_load_lds(
        (const __attribute__((address_space(1))) void*)g,
        (__attribute__((address_space(3))) void*)l, 16, 0, 0);
}

// ---------------------------------------------------------------------------
// x fp32 -> bf16, 8 elems/thread
// ---------------------------------------------------------------------------
__global__ __launch_bounds__(256) void cvt_bf16(
    const float* __restrict__ x, u16* __restrict__ xb) {
    size_t i = ((size_t)blockIdx.x * 256 + threadIdx.x) * 8;
    float4 u = *(const float4*)(x + i);
    float4 v = *(const float4*)(x + i + 4);
    uint4 p;
    p.x = pack2(u.x, u.y); p.y = pack2(u.z, u.w);
    p.z = pack2(v.x, v.y); p.w = pack2(v.z, v.w);
    *(uint4*)(xb + i) = p;
}

// ---------------------------------------------------------------------------
// Transpose+convert: W fp32 [2048 x ldW] (first `ncols` cols) -> WT bf16
// [ncols][2048]. 64x64 tiles. Grid (ncols/64, 32).
// ---------------------------------------------------------------------------
__global__ __launch_bounds__(256) void transpose_w(
    const float* __restrict__ W, int ldW, u16* __restrict__ WT) {
    __shared__ u16 tile[64][68];
    const int n0 = blockIdx.x * 64, k0 = blockIdx.y * 64;
    const int t = threadIdx.x;
    for (int i = t; i < 4096; i += 256) {
        int r = i >> 6, c = i & 63;
        tile[r][c] = f2bf(W[(size_t)(k0 + r) * ldW + n0 + c]);
    }
    __syncthreads();
    for (int i = t; i < 4096; i += 256) {
        int r = i >> 6, c = i & 63;          // r: n, c: k
        WT[(size_t)(n0 + r) * 2048 + k0 + c] = tile[c][r];
    }
}

// ---------------------------------------------------------------------------
// GEMM: C[M,N] = A[M,2048] @ Bt[N,2048].  M=4096, K=2048, N param.
// 128x128 tile, BK=32, 256 threads = 4 waves, each 64x64 (4x4 MFMA).
// amode 0: A fp32 flat (VGPR pack staging)          [fallback]
// amode 1: A bf16 BHTD gather, per-lane async16
// amode 2: A bf16 flat, async16
// amode 3: A bf16 BHTD gather, VGPR staging         [fallback]
// omode 0: fp32 store outf[M][N]
// omode 1: bf16 scatter -> Qo [BHTD]
// omode 2: bf16 scatter -> Vt [BHDT]
// omode 3: merged-qkv scatter (gn>>11 selects Qo/Ko/Vt)
// ---------------------------------------------------------------------------
__global__ __launch_bounds__(256) void gemm_k(
    const void* __restrict__ Av, const u16* __restrict__ Bt,
    int N, int amode, int omode,
    float* __restrict__ outf, u16* __restrict__ Qo, u16* __restrict__ Ko,
    u16* __restrict__ Vt) {
    const int K = 2048;
    __shared__ u16 As[128][32];
    __shared__ u16 Bs[128][32];

    const float* A32 = (const float*)Av;
    const u16*   A16 = (const u16*)Av;

    const int m0 = blockIdx.y * 128, n0 = blockIdx.x * 128;
    const int t = threadIdx.x;
    const int w = t >> 6, lane = t & 63;
    const int col = lane & 15, quad = lane >> 4;
    const int wrow = (w >> 1) * 64, wcol = (w & 1) * 64;

    f32x4 acc[4][4];
    #pragma unroll
    for (int i = 0; i < 4; ++i)
        #pragma unroll
        for (int j = 0; j < 4; ++j)
            acc[i][j] = (f32x4){0.f, 0.f, 0.f, 0.f};

    u16* as_flat = &As[0][0];
    u16* bs_flat = &Bs[0][0];
    const int c1 = (w << 6) | lane;      // 0..255
    const int c2 = c1 + 256;             // 256..511

    for (int k0 = 0; k0 < K; k0 += 32) {
        // ---- B tile: async16, 2 chunks/lane ----
        {
            const u16* g1 = Bt + (size_t)(n0 + (c1 >> 2)) * K + k0 + ((c1 & 3) << 3);
            async16(g1, bs_flat + (size_t)w * 512);
            const u16* g2 = Bt + (size_t)(n0 + (c2 >> 2)) * K + k0 + ((c2 & 3) << 3);
            async16(g2, bs_flat + 2048 + (size_t)w * 512);
        }
        // ---- A tile ----
        if (amode == 2) {
            const u16* g1 = A16 + (size_t)(m0 + (c1 >> 2)) * K + k0 + ((c1 & 3) << 3);
            async16(g1, as_flat + (size_t)w * 512);
            const u16* g2 = A16 + (size_t)(m0 + (c2 >> 2)) * K + k0 + ((c2 & 3) << 3);
            async16(g2, as_flat + 2048 + (size_t)w * 512);
        } else if (amode == 1) {
            #pragma unroll
            for (int cc = 0; cc < 2; ++cc) {
                int c = cc ? c2 : c1;
                int r = c >> 2, ko = (c & 3) << 3;
                int kg = k0 + ko, h = kg >> 7, d = kg & 127;
                int m = m0 + r, b = m >> 10, tt = m & 1023;
                const u16* g = A16 + (((size_t)(b * 16 + h)) * 1024 + tt) * 128 + d;
                async16(g, as_flat + (size_t)(cc ? 2048 : 0) + (size_t)w * 512);
            }
        } else if (amode == 0) {
            #pragma unroll
            for (int c = t; c < 512; c += 256) {
                int r = c >> 2, ko = (c & 3) * 8;
                size_t off = (size_t)(m0 + r) * K + k0 + ko;
                float4 u = *(const float4*)(A32 + off);
                float4 v = *(const float4*)(A32 + off + 4);
                uint4 p;
                p.x = pack2(u.x, u.y); p.y = pack2(u.z, u.w);
                p.z = pack2(v.x, v.y); p.w = pack2(v.z, v.w);
                *(uint4*)&As[r][ko] = p;
            }
        } else {  // amode 3: BHTD gather, VGPR staging
            #pragma unroll
            for (int c = t; c < 512; c += 256) {
                int r = c >> 2, ko = (c & 3) * 8;
                int kg = k0 + ko, h = kg >> 7, d = kg & 127;
                int m = m0 + r, b = m >> 10, tt = m & 1023;
                *(uint4*)&As[r][ko] =
                    *(const uint4*)(A16 + (((size_t)(b * 16 + h)) * 1024 + tt) * 128 + d);
            }
        }
        __syncthreads();

        bf16x8 afr[4], bfr[4];
        #pragma unroll
        for (int i = 0; i < 4; ++i)
            afr[i] = *(const bf16x8*)&As[wrow + i * 16 + col][quad * 8];
        #pragma unroll
        for (int i = 0; i < 4; ++i)
            bfr[i] = *(const bf16x8*)&Bs[wcol + i * 16 + col][quad * 8];

        #pragma unroll
        for (int mt = 0; mt < 4; ++mt)
            #pragma unroll
            for (int nt = 0; nt < 4; ++nt)
                acc[mt][nt] = mfma16(afr[mt], bfr[nt], acc[mt][nt]);
        __syncthreads();
    }

    // epilogue: C/D layout col = lane&15, row = quad*4 + r  (m89-verified)
    #pragma unroll
    for (int mt = 0; mt < 4; ++mt) {
        #pragma unroll
        for (int nt = 0; nt < 4; ++nt) {
            #pragma unroll
            for (int r = 0; r < 4; ++r) {
                int gm = m0 + wrow + mt * 16 + quad * 4 + r;
                int gn = n0 + wcol + nt * 16 + col;
                if (omode == 0) {
                    outf[(size_t)gm * N + gn] = acc[mt][nt][r];
                } else {
                    u16 bv = f2bf(acc[mt][nt][r]);
                    int b = gm >> 10, tq = gm & 1023;
                    if (omode == 3) {
                        int which = gn >> 11, rem = gn & 2047;
                        int h = rem >> 7, d = rem & 127;
                        size_t bh = (size_t)b * 16 + h;
                        if (which == 0)      Qo[(bh * 1024 + tq) * 128 + d] = bv;
                        else if (which == 1) Ko[(bh * 1024 + tq) * 128 + d] = bv;
                        else                 Vt[(bh * 128 + d) * 1024 + tq] = bv;
                    } else {
                        int h = gn >> 7, d = gn & 127;
                        size_t bh = (size_t)b * 16 + h;
                        if (omode == 1) Qo[(bh * 1024 + tq) * 128 + d] = bv;
                        else            Vt[(bh * 128 + d) * 1024 + tq] = bv;
                    }
                }
            }
        }
    }
}

// ---------------------------------------------------------------------------
// Flash attention. Grid (T/64, H, B), 256 threads = 4 waves; wave = 16 q-rows.
// qb reversed so heaviest blocks dispatch first. O overwrites Q in place.
// ---------------------------------------------------------------------------
__global__ __launch_bounds__(256) void attn_kernel(
    u16* __restrict__ Q, const u16* __restrict__ K,
    const u16* __restrict__ VT) {
    __shared__ u16 Ks[64][136];
    __shared__ u16 Vs[128][72];
    __shared__ u16 Ps[4][16][72];

    const int qb = (int)(gridDim.x - 1) - (int)blockIdx.x;   // heavy first
    const int h = blockIdx.y, b = blockIdx.z;
    const int t = threadIdx.x;
    const int w = t >> 6, lane = t & 63;
    const int col = lane & 15, quad = lane >> 4;
    const size_t bh = (size_t)b * 16 + h;
    u16* Qb = Q + bh * 1024 * 128;
    const u16* Kb = K + bh * 1024 * 128;
    const u16* Vb = VT + bh * 128 * 1024;
    const int qrow_w = qb * 64 + w * 16;

    bf16x8 qf[4];
    {
        const u16* qp = Qb + (size_t)(qrow_w + col) * 128 + quad * 8;
        #pragma unroll
        for (int kq = 0; kq < 4; ++kq)
            qf[kq] = *(const bf16x8*)(qp + kq * 32);
    }

    f32x4 o[8];
    #pragma unroll
    for (int i = 0; i < 8; ++i) o[i] = (f32x4){0.f, 0.f, 0.f, 0.f};
    float mrow[4], lrow[4];
    #pragma unroll
    for (int r = 0; r < 4; ++r) { mrow[r] = NEG_BIG; lrow[r] = 0.f; }

    const float scale = 0.08838834764831845f;  // 1/sqrt(128)
    const int nkt = qb + 1;

    for (int kt = 0; kt < nkt; ++kt) {
        #pragma unroll
        for (int c = t; c < 1024; c += 256) {
            int row = c >> 4, cc = (c & 15) * 8;
            *(uint4*)&Ks[row][cc] =
                *(const uint4*)(Kb + (size_t)(kt * 64 + row) * 128 + cc);
        }
        #pragma unroll
        for (int c = t; c < 1024; c += 256) {
            int d = c >> 3, cc = (c & 7) * 8;
            *(uint4*)&Vs[d][cc] =
                *(const uint4*)(Vb + (size_t)d * 1024 + kt * 64 + cc);
        }
        __syncthreads();

        f32x4 s[4];
        #pragma unroll
        for (int nt = 0; nt < 4; ++nt) {
            f32x4 a = (f32x4){0.f, 0.f, 0.f, 0.f};
            #pragma unroll
            for (int kq = 0; kq < 4; ++kq) {
                bf16x8 kf = *(const bf16x8*)&Ks[nt * 16 + col][kq * 32 + quad * 8];
                a = mfma16(qf[kq], kf, a);
            }
            s[nt] = a;
        }

        const bool need_mask = (kt == qb);
        float rmax[4];
        #pragma unroll
        for (int r = 0; r < 4; ++r) rmax[r] = NEG_BIG;
        #pragma unroll
        for (int nt = 0; nt < 4; ++nt) {
            int kcol = kt * 64 + nt * 16 + col;
            #pragma unroll
            for (int r = 0; r < 4; ++r) {
                float v = s[nt][r] * scale;
                int qr = qrow_w + quad * 4 + r;
                if (need_mask && kcol > qr) v = NEG_BIG;
                s[nt][r] = v;
                rmax[r] = fmaxf(rmax[r], v);
            }
        }
        #pragma unroll
        for (int msk = 1; msk < 16; msk <<= 1)
            #pragma unroll
            for (int r = 0; r < 4; ++r)
                rmax[r] = fmaxf(rmax[r], __shfl_xor(rmax[r], msk, 64));

        float alpha[4], rsum[4];
        #pragma unroll
        for (int r = 0; r < 4; ++r) {
            float mnew = fmaxf(mrow[r], rmax[r]);
            alpha[r] = __expf(mrow[r] - mnew);
            mrow[r] = mnew;
            rsum[r] = 0.f;
        }
        #pragma unroll
        for (int nt = 0; nt < 4; ++nt) {
            #pragma unroll
            for (int r = 0; r < 4; ++r) {
                float p = __expf(s[nt][r] - mrow[r]);
                rsum[r] += p;
                Ps[w][quad * 4 + r][nt * 16 + col] = f2bf(p);
            }
        }
        #pragma unroll
        for (int msk = 1; msk < 16; msk <<= 1)
            #pragma unroll
            for (int r = 0; r < 4; ++r)
                rsum[r] += __shfl_xor(rsum[r], msk, 64);
        #pragma unroll
        for (int r = 0; r < 4; ++r) lrow[r] = lrow[r] * alpha[r] + rsum[r];
        #pragma unroll
        for (int dt = 0; dt < 8; ++dt)
            #pragma unroll
            for (int r = 0; r < 4; ++r) o[dt][r] *= alpha[r];

        #pragma unroll
        for (int ks = 0; ks < 2; ++ks) {
            bf16x8 pf = *(const bf16x8*)&Ps[w][col][ks * 32 + quad * 8];
            #pragma unroll
            for (int dt = 0; dt < 8; ++dt) {
                bf16x8 vf = *(const bf16x8*)&Vs[dt * 16 + col][ks * 32 + quad * 8];
                o[dt] = mfma16(pf, vf, o[dt]);
            }
        }
        __syncthreads();
    }

    #pragma unroll
    for (int dt = 0; dt < 8; ++dt) {
        #pragma unroll
        for (int r = 0; r < 4; ++r) {
            int tq = qrow_w + quad * 4 + r;
            Qb[((size_t)tq) * 128 + dt * 16 + col] = f2bf(o[dt][r] / lrow[r]);
        }
    }
}

// ---------------------------------------------------------------------------
extern "C" void kernel_launch(void* const* d_in, const int* in_sizes, int n_in,
                              void* d_out, int out_size, void* d_ws, size_t ws_size,
                              hipStream_t stream) {
    const float* x      = (const float*)d_in[0];   // [4096, 2048]
    const float* w_qkv  = (const float*)d_in[1];   // [2048, 6144]
    const float* w_proj = (const float*)d_in[2];   // [2048, 2048]
    float* out = (float*)d_out;                    // [4096, 2048]

    const size_t SEG = (size_t)4 * 16 * 1024 * 128;      // 8,388,608 elems
    const size_t NEED_FAST = ((size_t)6144 * 2048 + SEG * 4) * 2;  // 92.3 MB

    if (ws_size >= NEED_FAST + (1u << 20)) {
        // ---------------- fast path ----------------
        u16* wT = (u16*)d_ws;                 // 6144*2048 (qkv), reused for proj
        u16* xb = wT + (size_t)6144 * 2048;
        u16* Qb = xb + SEG;
        u16* Kb = Qb + SEG;
        u16* Vb = Kb + SEG;

        cvt_bf16<<<4096, 256, 0, stream>>>(x, xb);
        transpose_w<<<dim3(96, 32), 256, 0, stream>>>(w_qkv, 6144, wT);

        // QKV = xb @ wqkvT, merged (1536 blocks, both operands async16)
        gemm_k<<<dim3(48, 32), 256, 0, stream>>>(xb, wT, 6144, 2, 3,
                                                 nullptr, Qb, Kb, Vb);

        attn_kernel<<<dim3(16, 16, 4), 256, 0, stream>>>(Qb, Kb, Vb);

        transpose_w<<<dim3(32, 32), 256, 0, stream>>>(w_proj, 2048, wT);
        gemm_k<<<dim3(16, 32), 256, 0, stream>>>(Qb, wT, 2048, 1, 0,
                                                 out, nullptr, nullptr, nullptr);
    } else {
        // ---------------- R5-proven fallback (ws >= 58.7 MB) ----------------
        u16* wT = (u16*)d_ws;                 // 2048*2048
        u16* Qb = wT + (size_t)2048 * 2048;
        u16* Kb = Qb + SEG;
        u16* Vb = Kb + SEG;

        transpose_w<<<dim3(32, 32), 256, 0, stream>>>(w_qkv + 0, 6144, wT);
        gemm_k<<<dim3(16, 32), 256, 0, stream>>>(x, wT, 2048, 0, 1,
                                                 nullptr, Qb, nullptr, nullptr);
        transpose_w<<<dim3(32, 32), 256, 0, stream>>>(w_qkv + 2048, 6144, wT);
        gemm_k<<<dim3(16, 32), 256, 0, stream>>>(x, wT, 2048, 0, 1,
                                                 nullptr, Kb, nullptr, nullptr);
        transpose_w<<<dim3(32, 32), 256, 0, stream>>>(w_qkv + 4096, 6144, wT);
        gemm_k<<<dim3(16, 32), 256, 0, stream>>>(x, wT, 2048, 0, 2,
                                                 nullptr, nullptr, nullptr, Vb);

        attn_kernel<<<dim3(16, 16, 4), 256, 0, stream>>>(Qb, Kb, Vb);

        transpose_w<<<dim3(32, 32), 256, 0, stream>>>(w_proj, 2048, wT);
        gemm_k<<<dim3(16, 32), 256, 0, stream>>>(Qb, wT, 2048, 3, 0,
                                                 out, nullptr, nullptr, nullptr);
    }
}